// Round 2
// baseline (2272.596 us; speedup 1.0000x reference)
//
#include <hip/hip_runtime.h>
#include <math.h>

#define NN 100000
#define NE 1600000
constexpr int IN_DIM = 128;
constexpr int ED_DIM = 16;
constexpr int D = 16;
constexpr int CD = 8;
constexpr int C = 10;

__device__ __forceinline__ float leaky(float v) { return v >= 0.f ? v : 0.01f * v; }

// ---------------- zero workspace region ----------------
__global__ __launch_bounds__(256) void k_zero(float* __restrict__ p, int n) {
    int i = blockIdx.x * 256 + threadIdx.x;
    if (i < n) p[i] = 0.f;
}

// ---------------- node encoder: h = (leaky(x@w1+b1)@w2+b2) * (tw*tww+twb) ----------------
__global__ __launch_bounds__(256) void k_node_enc(
    const float* __restrict__ x, const float* __restrict__ twin,
    const float* __restrict__ w1, const float* __restrict__ b1,
    const float* __restrict__ w2, const float* __restrict__ b2,
    const float* __restrict__ tww, const float* __restrict__ twb,
    float* __restrict__ hout) {
    int i = blockIdx.x * 256 + threadIdx.x;
    if (i >= NN) return;
    float acc[D];
#pragma unroll
    for (int j = 0; j < D; ++j) acc[j] = b1[j];
    const float4* xr = reinterpret_cast<const float4*>(x + (size_t)i * IN_DIM);
#pragma unroll 8
    for (int k4 = 0; k4 < IN_DIM / 4; ++k4) {
        float4 xv = xr[k4];
        const float* wr = w1 + (k4 * 4) * D;
#pragma unroll
        for (int j = 0; j < D; ++j) acc[j] += xv.x * wr[j];
#pragma unroll
        for (int j = 0; j < D; ++j) acc[j] += xv.y * wr[D + j];
#pragma unroll
        for (int j = 0; j < D; ++j) acc[j] += xv.z * wr[2 * D + j];
#pragma unroll
        for (int j = 0; j < D; ++j) acc[j] += xv.w * wr[3 * D + j];
    }
    float t[D];
#pragma unroll
    for (int j = 0; j < D; ++j) t[j] = leaky(acc[j]);
    float h2[D];
#pragma unroll
    for (int j = 0; j < D; ++j) h2[j] = b2[j];
#pragma unroll
    for (int k = 0; k < D; ++k)
#pragma unroll
        for (int j = 0; j < D; ++j) h2[j] += t[k] * w2[k * D + j];
    float twv = twin[i];
#pragma unroll
    for (int j = 0; j < D; ++j) h2[j] *= (twv * tww[j] + twb[j]);
    float4* ho = reinterpret_cast<float4*>(hout + (size_t)i * D);
#pragma unroll
    for (int q = 0; q < 4; ++q)
        ho[q] = make_float4(h2[4 * q], h2[4 * q + 1], h2[4 * q + 2], h2[4 * q + 3]);
}

// ---------------- conv1 messages: per edge, edge-enc + MLP(32->32->32->8) + atomic scatter ----------------
__global__ __launch_bounds__(256) void k_conv1(
    const float* __restrict__ earaw, const int* __restrict__ ei,
    const float* __restrict__ h,
    const float* __restrict__ ew1, const float* __restrict__ eb1,
    const float* __restrict__ ew2, const float* __restrict__ eb2,
    const float* __restrict__ w1, const float* __restrict__ b1,
    const float* __restrict__ w2, const float* __restrict__ b2,
    const float* __restrict__ w3, const float* __restrict__ b3,
    float* __restrict__ agg) {
    int e = blockIdx.x * 256 + threadIdx.x;
    if (e >= NE) return;
    int src = ei[e];
    int dst = ei[NE + e];
    // edge encoder
    float r[ED_DIM];
    const float4* er = reinterpret_cast<const float4*>(earaw + (size_t)e * ED_DIM);
#pragma unroll
    for (int q = 0; q < 4; ++q) {
        float4 v = er[q];
        r[4 * q] = v.x; r[4 * q + 1] = v.y; r[4 * q + 2] = v.z; r[4 * q + 3] = v.w;
    }
    float t[D];
#pragma unroll
    for (int j = 0; j < D; ++j) t[j] = eb1[j];
#pragma unroll
    for (int k = 0; k < ED_DIM; ++k)
#pragma unroll
        for (int j = 0; j < D; ++j) t[j] += r[k] * ew1[k * D + j];
#pragma unroll
    for (int j = 0; j < D; ++j) t[j] = leaky(t[j]);
    float a[2 * D];
#pragma unroll
    for (int j = 0; j < D; ++j) a[D + j] = eb2[j];
#pragma unroll
    for (int k = 0; k < D; ++k)
#pragma unroll
        for (int j = 0; j < D; ++j) a[D + j] += t[k] * ew2[k * D + j];
    // gather h[src]
    const float4* hr = reinterpret_cast<const float4*>(h + (size_t)src * D);
#pragma unroll
    for (int q = 0; q < 4; ++q) {
        float4 v = hr[q];
        a[4 * q] = v.x; a[4 * q + 1] = v.y; a[4 * q + 2] = v.z; a[4 * q + 3] = v.w;
    }
    // layer1 32->32
    float bv[2 * D];
#pragma unroll
    for (int j = 0; j < 32; ++j) bv[j] = b1[j];
#pragma unroll
    for (int k = 0; k < 32; ++k)
#pragma unroll
        for (int j = 0; j < 32; ++j) bv[j] += a[k] * w1[k * 32 + j];
#pragma unroll
    for (int j = 0; j < 32; ++j) bv[j] = leaky(bv[j]);
    // layer2 32->32
#pragma unroll
    for (int j = 0; j < 32; ++j) a[j] = b2[j];
#pragma unroll
    for (int k = 0; k < 32; ++k)
#pragma unroll
        for (int j = 0; j < 32; ++j) a[j] += bv[k] * w2[k * 32 + j];
#pragma unroll
    for (int j = 0; j < 32; ++j) a[j] = leaky(a[j]);
    // layer3 32->8
    float o[CD];
#pragma unroll
    for (int j = 0; j < CD; ++j) o[j] = b3[j];
#pragma unroll
    for (int k = 0; k < 32; ++k)
#pragma unroll
        for (int j = 0; j < CD; ++j) o[j] += a[k] * w3[k * CD + j];
    float* ap = agg + (size_t)dst * CD;
#pragma unroll
    for (int j = 0; j < CD; ++j) atomicAdd(ap + j, o[j]);
}

// ---------------- node update 1: x1pre = relu(agg + h@root1 + bias1), BN partial sums ----------------
__global__ __launch_bounds__(256) void k_node1(
    const float* __restrict__ agg, const float* __restrict__ h,
    const float* __restrict__ root1, const float* __restrict__ bias1,
    float* __restrict__ x1pre, float* __restrict__ bnstat) {
    int i = blockIdx.x * 256 + threadIdx.x;
    float v[CD], sq[CD];
    if (i < NN) {
        float hv[D];
        const float4* hr = reinterpret_cast<const float4*>(h + (size_t)i * D);
#pragma unroll
        for (int q = 0; q < 4; ++q) {
            float4 w = hr[q];
            hv[4 * q] = w.x; hv[4 * q + 1] = w.y; hv[4 * q + 2] = w.z; hv[4 * q + 3] = w.w;
        }
#pragma unroll
        for (int j = 0; j < CD; ++j) v[j] = bias1[j] + agg[(size_t)i * CD + j];
#pragma unroll
        for (int k = 0; k < D; ++k)
#pragma unroll
            for (int j = 0; j < CD; ++j) v[j] += hv[k] * root1[k * CD + j];
#pragma unroll
        for (int j = 0; j < CD; ++j) v[j] = fmaxf(v[j], 0.f);
#pragma unroll
        for (int j = 0; j < CD; ++j) x1pre[(size_t)i * CD + j] = v[j];
    } else {
#pragma unroll
        for (int j = 0; j < CD; ++j) v[j] = 0.f;
    }
#pragma unroll
    for (int j = 0; j < CD; ++j) sq[j] = v[j] * v[j];
#pragma unroll
    for (int off = 32; off > 0; off >>= 1) {
#pragma unroll
        for (int j = 0; j < CD; ++j) {
            v[j] += __shfl_down(v[j], off);
            sq[j] += __shfl_down(sq[j], off);
        }
    }
    if ((threadIdx.x & 63) == 0) {
#pragma unroll
        for (int j = 0; j < CD; ++j) {
            atomicAdd(&bnstat[j], v[j]);
            atomicAdd(&bnstat[CD + j], sq[j]);
        }
    }
}

// ---------------- BN finalize: scale/shift ----------------
__global__ void k_bnfin(const float* __restrict__ bnstat, const float* __restrict__ gamma,
                        const float* __restrict__ beta, float* __restrict__ sc) {
    int j = threadIdx.x;
    if (j < CD) {
        float mu = bnstat[j] / (float)NN;
        float var = bnstat[CD + j] / (float)NN - mu * mu;
        float inv = rsqrtf(var + 1e-5f);
        float s = gamma[j] * inv;
        sc[j] = s;
        sc[CD + j] = beta[j] - mu * s;
    }
}

// ---------------- conv2 messages: per edge, edge-enc + affine(x1pre[src]) + MLP(24->24->24->10) ----------------
__global__ __launch_bounds__(256) void k_conv2(
    const float* __restrict__ earaw, const int* __restrict__ ei,
    const float* __restrict__ x1pre, const float* __restrict__ sc,
    const float* __restrict__ ew1, const float* __restrict__ eb1,
    const float* __restrict__ ew2, const float* __restrict__ eb2,
    const float* __restrict__ w1, const float* __restrict__ b1,
    const float* __restrict__ w2, const float* __restrict__ b2,
    const float* __restrict__ w3, const float* __restrict__ b3,
    float* __restrict__ agg2) {
    int e = blockIdx.x * 256 + threadIdx.x;
    if (e >= NE) return;
    int src = ei[e];
    int dst = ei[NE + e];
    constexpr int M = CD + D;  // 24
    // edge encoder
    float r[ED_DIM];
    const float4* er = reinterpret_cast<const float4*>(earaw + (size_t)e * ED_DIM);
#pragma unroll
    for (int q = 0; q < 4; ++q) {
        float4 v = er[q];
        r[4 * q] = v.x; r[4 * q + 1] = v.y; r[4 * q + 2] = v.z; r[4 * q + 3] = v.w;
    }
    float t[D];
#pragma unroll
    for (int j = 0; j < D; ++j) t[j] = eb1[j];
#pragma unroll
    for (int k = 0; k < ED_DIM; ++k)
#pragma unroll
        for (int j = 0; j < D; ++j) t[j] += r[k] * ew1[k * D + j];
#pragma unroll
    for (int j = 0; j < D; ++j) t[j] = leaky(t[j]);
    float a[M];
#pragma unroll
    for (int j = 0; j < D; ++j) a[CD + j] = eb2[j];
#pragma unroll
    for (int k = 0; k < D; ++k)
#pragma unroll
        for (int j = 0; j < D; ++j) a[CD + j] += t[k] * ew2[k * D + j];
    // gather x1pre[src] + affine (BN)
    const float4* xr = reinterpret_cast<const float4*>(x1pre + (size_t)src * CD);
    float xv[CD];
#pragma unroll
    for (int q = 0; q < 2; ++q) {
        float4 v = xr[q];
        xv[4 * q] = v.x; xv[4 * q + 1] = v.y; xv[4 * q + 2] = v.z; xv[4 * q + 3] = v.w;
    }
#pragma unroll
    for (int j = 0; j < CD; ++j) a[j] = xv[j] * sc[j] + sc[CD + j];
    // layer1 24->24
    float bv[M];
#pragma unroll
    for (int j = 0; j < M; ++j) bv[j] = b1[j];
#pragma unroll
    for (int k = 0; k < M; ++k)
#pragma unroll
        for (int j = 0; j < M; ++j) bv[j] += a[k] * w1[k * M + j];
#pragma unroll
    for (int j = 0; j < M; ++j) bv[j] = leaky(bv[j]);
    // layer2 24->24
#pragma unroll
    for (int j = 0; j < M; ++j) a[j] = b2[j];
#pragma unroll
    for (int k = 0; k < M; ++k)
#pragma unroll
        for (int j = 0; j < M; ++j) a[j] += bv[k] * w2[k * M + j];
#pragma unroll
    for (int j = 0; j < M; ++j) a[j] = leaky(a[j]);
    // layer3 24->10
    float o[C];
#pragma unroll
    for (int j = 0; j < C; ++j) o[j] = b3[j];
#pragma unroll
    for (int k = 0; k < M; ++k)
#pragma unroll
        for (int j = 0; j < C; ++j) o[j] += a[k] * w3[k * C + j];
    float* ap = agg2 + (size_t)dst * C;
#pragma unroll
    for (int j = 0; j < C; ++j) atomicAdd(ap + j, o[j]);
}

// ---------------- final: x2 = relu(agg2 + x1n@root2 + bias2); log_softmax(concat@fc) ----------------
__global__ __launch_bounds__(256) void k_final(
    const float* __restrict__ x1pre, const float* __restrict__ sc,
    const float* __restrict__ agg2, const float* __restrict__ root2,
    const float* __restrict__ bias2, const float* __restrict__ fcw,
    const float* __restrict__ fcb, float* __restrict__ out) {
    int i = blockIdx.x * 256 + threadIdx.x;
    if (i >= NN) return;
    float z[CD + C];  // 18
    const float4* xr = reinterpret_cast<const float4*>(x1pre + (size_t)i * CD);
#pragma unroll
    for (int q = 0; q < 2; ++q) {
        float4 v = xr[q];
        z[4 * q] = v.x; z[4 * q + 1] = v.y; z[4 * q + 2] = v.z; z[4 * q + 3] = v.w;
    }
#pragma unroll
    for (int j = 0; j < CD; ++j) z[j] = z[j] * sc[j] + sc[CD + j];
    float x2[C];
#pragma unroll
    for (int j = 0; j < C; ++j) x2[j] = bias2[j] + agg2[(size_t)i * C + j];
#pragma unroll
    for (int k = 0; k < CD; ++k)
#pragma unroll
        for (int j = 0; j < C; ++j) x2[j] += z[k] * root2[k * C + j];
#pragma unroll
    for (int j = 0; j < C; ++j) z[CD + j] = fmaxf(x2[j], 0.f);
    float lg[C];
#pragma unroll
    for (int j = 0; j < C; ++j) lg[j] = fcb[j];
#pragma unroll
    for (int k = 0; k < CD + C; ++k)
#pragma unroll
        for (int j = 0; j < C; ++j) lg[j] += z[k] * fcw[k * C + j];
    float mx = lg[0];
#pragma unroll
    for (int j = 1; j < C; ++j) mx = fmaxf(mx, lg[j]);
    float se = 0.f;
#pragma unroll
    for (int j = 0; j < C; ++j) se += __expf(lg[j] - mx);
    float ls = __logf(se) + mx;
    float* op = out + (size_t)i * C;
#pragma unroll
    for (int j = 0; j < C; ++j) op[j] = lg[j] - ls;
}

extern "C" void kernel_launch(void* const* d_in, const int* in_sizes, int n_in,
                              void* d_out, int out_size, void* d_ws, size_t ws_size,
                              hipStream_t stream) {
    const float* x      = (const float*)d_in[0];
    const float* earaw  = (const float*)d_in[1];
    const float* twin   = (const float*)d_in[2];
    const int*   ei     = (const int*)d_in[3];
    const float* ne_w1  = (const float*)d_in[4];
    const float* ne_b1  = (const float*)d_in[5];
    const float* ne_w2  = (const float*)d_in[6];
    const float* ne_b2  = (const float*)d_in[7];
    const float* ee_w1  = (const float*)d_in[8];
    const float* ee_b1  = (const float*)d_in[9];
    const float* ee_w2  = (const float*)d_in[10];
    const float* ee_b2  = (const float*)d_in[11];
    const float* tw_w   = (const float*)d_in[12];
    const float* tw_b   = (const float*)d_in[13];
    const float* nn1_w1 = (const float*)d_in[14];
    const float* nn1_b1 = (const float*)d_in[15];
    const float* nn1_w2 = (const float*)d_in[16];
    const float* nn1_b2 = (const float*)d_in[17];
    const float* nn1_w3 = (const float*)d_in[18];
    const float* nn1_b3 = (const float*)d_in[19];
    const float* root1  = (const float*)d_in[20];
    const float* bias1  = (const float*)d_in[21];
    const float* bn_g   = (const float*)d_in[22];
    const float* bn_b   = (const float*)d_in[23];
    const float* nn2_w1 = (const float*)d_in[24];
    const float* nn2_b1 = (const float*)d_in[25];
    const float* nn2_w2 = (const float*)d_in[26];
    const float* nn2_b2 = (const float*)d_in[27];
    const float* nn2_w3 = (const float*)d_in[28];
    const float* nn2_b3 = (const float*)d_in[29];
    const float* root2  = (const float*)d_in[30];
    const float* bias2  = (const float*)d_in[31];
    const float* fc_w   = (const float*)d_in[32];
    const float* fc_b   = (const float*)d_in[33];
    float* out = (float*)d_out;
    float* ws = (float*)d_ws;

    float* h      = ws;                       // NN*16
    float* x1pre  = ws + (size_t)NN * 16;     // NN*8
    float* agg    = ws + (size_t)NN * 24;     // NN*8   (zeroed)
    float* agg2   = ws + (size_t)NN * 32;     // NN*10  (zeroed)
    float* bnstat = ws + (size_t)NN * 42;     // 16     (zeroed)
    float* sc     = bnstat + 16;              // 16

    int zn = NN * 18 + 16;  // agg + agg2 + bnstat
    k_zero<<<(zn + 255) / 256, 256, 0, stream>>>(agg, zn);
    k_node_enc<<<(NN + 255) / 256, 256, 0, stream>>>(
        x, twin, ne_w1, ne_b1, ne_w2, ne_b2, tw_w, tw_b, h);
    k_conv1<<<(NE + 255) / 256, 256, 0, stream>>>(
        earaw, ei, h, ee_w1, ee_b1, ee_w2, ee_b2,
        nn1_w1, nn1_b1, nn1_w2, nn1_b2, nn1_w3, nn1_b3, agg);
    k_node1<<<(NN + 255) / 256, 256, 0, stream>>>(
        agg, h, root1, bias1, x1pre, bnstat);
    k_bnfin<<<1, 64, 0, stream>>>(bnstat, bn_g, bn_b, sc);
    k_conv2<<<(NE + 255) / 256, 256, 0, stream>>>(
        earaw, ei, x1pre, sc, ee_w1, ee_b1, ee_w2, ee_b2,
        nn2_w1, nn2_b1, nn2_w2, nn2_b2, nn2_w3, nn2_b3, agg2);
    k_final<<<(NN + 255) / 256, 256, 0, stream>>>(
        x1pre, sc, agg2, root2, bias2, fc_w, fc_b, out);
}